// Round 11
// baseline (104.566 us; speedup 1.0000x reference)
//
#include <hip/hip_runtime.h>
#include <hip/hip_bf16.h>

#define TWO_N 8192
#define NHALF 4096
#define D 256
#define NTILE 64            // 8192 / 128 tiles per dimension
#define NTRI  2080          // NTILE*(NTILE+1)/2 live triangle tiles (= 8*260)
#define NPROBE 520          // quarter-scale probe tile count
#define BLK_ELEMS 32768     // 32 kchunks * 128 rows * 8 elems per 128-row block
static constexpr float INV_T = 2.0f; // 1 / 0.5

typedef __attribute__((ext_vector_type(8))) short short8;
typedef __attribute__((ext_vector_type(4))) float f32x4;

#define AS1 __attribute__((address_space(1)))
#define AS3 __attribute__((address_space(3)))

__device__ __forceinline__ ushort f2bfu(float f) {
    __hip_bfloat16 b = __float2bfloat16(f);
    return *reinterpret_cast<ushort*>(&b);
}

// ------ kernel 1: fused normalize + positive-pair sim, blocked-K-major out --
// znb layout: [rowblock(64)][kchunk(32)][row-in-block(128)][elem(8)]
__global__ __launch_bounds__(256) void norm_pos_kernel(
        const float* __restrict__ z_i, const float* __restrict__ z_j,
        ushort* __restrict__ znb, float* __restrict__ sim_pos,
        float* __restrict__ denom) {
    const int wid = threadIdx.x >> 6, lane = threadIdx.x & 63;
    const int i = blockIdx.x * 4 + wid;  // 0..4095
    const float4 vi = *reinterpret_cast<const float4*>(z_i + (size_t)i * D + lane * 4);
    const float4 vj = *reinterpret_cast<const float4*>(z_j + (size_t)i * D + lane * 4);
    float ssi = vi.x * vi.x + vi.y * vi.y + vi.z * vi.z + vi.w * vi.w;
    float ssj = vj.x * vj.x + vj.y * vj.y + vj.z * vj.z + vj.w * vj.w;
    float dt  = vi.x * vj.x + vi.y * vj.y + vi.z * vj.z + vi.w * vj.w;
    #pragma unroll
    for (int off = 32; off; off >>= 1) {
        ssi += __shfl_xor(ssi, off);
        ssj += __shfl_xor(ssj, off);
        dt  += __shfl_xor(dt,  off);
    }
    const float ri = rsqrtf(ssi), rj = rsqrtf(ssj);
    ushort4 oi, oj;
    oi.x = f2bfu(vi.x * ri); oi.y = f2bfu(vi.y * ri);
    oi.z = f2bfu(vi.z * ri); oi.w = f2bfu(vi.w * ri);
    oj.x = f2bfu(vj.x * rj); oj.y = f2bfu(vj.y * rj);
    oj.z = f2bfu(vj.z * rj); oj.w = f2bfu(vj.w * rj);
    const int c = lane >> 1, e = (lane & 1) * 4;
    const int i2 = i + NHALF;
    const size_t bi = ((size_t)(i  >> 7) * 32 + c) * 1024 + (i  & 127) * 8 + e;
    const size_t bj = ((size_t)(i2 >> 7) * 32 + c) * 1024 + (i2 & 127) * 8 + e;
    *reinterpret_cast<ushort4*>(znb + bi) = oi;
    *reinterpret_cast<ushort4*>(znb + bj) = oj;
    if (lane == 0) {
        const float sp = dt * ri * rj * INV_T;
        sim_pos[i] = sp;
        sim_pos[i + NHALF] = sp;   // symmetric
        denom[i] = 0.0f;
        denom[i + NHALF] = 0.0f;
    }
}

// ======== shared GEMM body pieces (R7-exact geometry & schedule) ========
// BM=BN=128, BK=32, 4 waves (2x2), ring-3 counted-vmcnt, blocked sources.

#define GEMM_SETUP                                                              \
    const int tid  = threadIdx.x;                                               \
    const int lane = tid & 63;                                                  \
    const int wid  = tid >> 6;                                                  \
    const int wr   = wid >> 1;                                                  \
    const int wc   = wid & 1;                                                   \
    const int r16  = lane & 15;                                                 \
    const int kgrp = lane >> 4;                                                 \
    const int row0 = tr * 128;                                                  \
    const int col0 = tc * 128;                                                  \
    const ushort* gA = znb + (size_t)tr * BLK_ELEMS + tid * 8;                  \
    const ushort* gB = znb + (size_t)tc * BLK_ELEMS + tid * 8;                  \
    const int d0 = (0 * 256 + wid * 64) * 8;                                    \
    const int d1 = (1 * 256 + wid * 64) * 8;

#define STAGE(buf, koff)                                                        \
    do {                                                                        \
        __builtin_amdgcn_global_load_lds((const AS1 void*)(gA + (koff)),        \
            (AS3 void*)(As[buf] + d0), 16, 0, 0);                               \
        __builtin_amdgcn_global_load_lds((const AS1 void*)(gA + (koff) + 2048), \
            (AS3 void*)(As[buf] + d1), 16, 0, 0);                               \
        __builtin_amdgcn_global_load_lds((const AS1 void*)(gB + (koff)),        \
            (AS3 void*)(Bs[buf] + d0), 16, 0, 0);                               \
        __builtin_amdgcn_global_load_lds((const AS1 void*)(gB + (koff) + 2048), \
            (AS3 void*)(Bs[buf] + d1), 16, 0, 0);                               \
    } while (0)

// ------ kernel 2 (PRODUCTION): R7 + compact triangle grid + XCD chunk swizzle
// tile = (bid%8)*260 + bid/8 : each XCD gets a contiguous 260-tile run of the
// triangle -> consecutive tiles share the A panel -> A reads are XCD-local L2.
__global__ __launch_bounds__(256) void gemm_denom_kernel(
        const ushort* __restrict__ znb, float* __restrict__ denom) {
    const int t = (blockIdx.x & 7) * (NTRI / 8) + (blockIdx.x >> 3);
    int rem = t;
    int tr = 0;
    while (rem >= NTILE - tr) { rem -= NTILE - tr; ++tr; }
    const int tc = tr + rem;

    __shared__ ushort As[3][4 * 128 * 8];  // 3 x 8 KB
    __shared__ ushort Bs[3][4 * 128 * 8];

    GEMM_SETUP

    f32x4 acc[4][4];
    #pragma unroll
    for (int m = 0; m < 4; ++m)
        #pragma unroll
        for (int n = 0; n < 4; ++n) {
            f32x4 z = {0.f, 0.f, 0.f, 0.f};
            acc[m][n] = z;
        }

    STAGE(0, 0);
    STAGE(1, 4096);

    #pragma unroll
    for (int ks = 0; ks < 8; ++ks) {
        const int cur = ks % 3;
        if (ks < 7) asm volatile("s_waitcnt vmcnt(4)" ::: "memory");
        else        asm volatile("s_waitcnt vmcnt(0)" ::: "memory");
        __builtin_amdgcn_s_barrier();
        asm volatile("" ::: "memory");
        if (ks < 6) STAGE((ks + 2) % 3, (ks + 2) * 4096);
        short8 a[4], b[4];
        #pragma unroll
        for (int m = 0; m < 4; ++m)
            a[m] = *reinterpret_cast<const short8*>(
                As[cur] + ((kgrp * 128) + wr * 64 + m * 16 + r16) * 8);
        #pragma unroll
        for (int n = 0; n < 4; ++n)
            b[n] = *reinterpret_cast<const short8*>(
                Bs[cur] + ((kgrp * 128) + wc * 64 + n * 16 + r16) * 8);
        #pragma unroll
        for (int m = 0; m < 4; ++m)
            #pragma unroll
            for (int n = 0; n < 4; ++n)
                acc[m][n] = __builtin_amdgcn_mfma_f32_16x16x32_bf16(
                    a[m], b[n], acc[m][n], 0, 0, 0);
    }

    const bool offdiag = (tr != tc);
    float cs[4] = {0.f, 0.f, 0.f, 0.f};
    #pragma unroll
    for (int m = 0; m < 4; ++m) {
        #pragma unroll
        for (int reg = 0; reg < 4; ++reg) {
            const int rg = row0 + wr * 64 + m * 16 + kgrp * 4 + reg;
            float rs = 0.f;
            #pragma unroll
            for (int n = 0; n < 4; ++n) {
                const int cg = col0 + wc * 64 + n * 16 + r16;
                float e = __expf(acc[m][n][reg] * INV_T);
                if (rg == cg) e = 0.f;
                rs += e;
                cs[n] += e;
            }
            rs += __shfl_xor(rs, 1);
            rs += __shfl_xor(rs, 2);
            rs += __shfl_xor(rs, 4);
            rs += __shfl_xor(rs, 8);
            if (r16 == 0) atomicAdd(&denom[rg], rs);
        }
    }
    if (offdiag) {
        #pragma unroll
        for (int n = 0; n < 4; ++n) {
            cs[n] += __shfl_xor(cs[n], 16);
            cs[n] += __shfl_xor(cs[n], 32);
        }
        if (kgrp == 0) {
            #pragma unroll
            for (int n = 0; n < 4; ++n)
                atomicAdd(&denom[col0 + wc * 64 + n * 16 + r16], cs[n]);
        }
    }
}

// ------ ablation probes: MODE 0 = stage-only, 1 = +ds_read+MFMA, 2 = full ----
// Quarter-scale (520 tiles), write only to probe scratch. Distinct kernel
// names appear as separate dispatches in the rocprof table -> per-phase cost.
template<int MODE>
__global__ __launch_bounds__(256) void gemm_probe(
        const ushort* __restrict__ znb, float* __restrict__ pden,
        float* __restrict__ sink) {
    int rem = blockIdx.x;
    int tr = 0;
    while (rem >= NTILE - tr) { rem -= NTILE - tr; ++tr; }
    const int tc = tr + rem;

    __shared__ ushort As[3][4 * 128 * 8];
    __shared__ ushort Bs[3][4 * 128 * 8];

    GEMM_SETUP

    f32x4 acc[4][4];
    #pragma unroll
    for (int m = 0; m < 4; ++m)
        #pragma unroll
        for (int n = 0; n < 4; ++n) {
            f32x4 z = {0.f, 0.f, 0.f, 0.f};
            acc[m][n] = z;
        }

    STAGE(0, 0);
    STAGE(1, 4096);

    #pragma unroll
    for (int ks = 0; ks < 8; ++ks) {
        const int cur = ks % 3;
        if (ks < 7) asm volatile("s_waitcnt vmcnt(4)" ::: "memory");
        else        asm volatile("s_waitcnt vmcnt(0)" ::: "memory");
        __builtin_amdgcn_s_barrier();
        asm volatile("" ::: "memory");
        if (ks < 6) STAGE((ks + 2) % 3, (ks + 2) * 4096);
        if constexpr (MODE >= 1) {
            short8 a[4], b[4];
            #pragma unroll
            for (int m = 0; m < 4; ++m)
                a[m] = *reinterpret_cast<const short8*>(
                    As[cur] + ((kgrp * 128) + wr * 64 + m * 16 + r16) * 8);
            #pragma unroll
            for (int n = 0; n < 4; ++n)
                b[n] = *reinterpret_cast<const short8*>(
                    Bs[cur] + ((kgrp * 128) + wc * 64 + n * 16 + r16) * 8);
            #pragma unroll
            for (int m = 0; m < 4; ++m)
                #pragma unroll
                for (int n = 0; n < 4; ++n)
                    acc[m][n] = __builtin_amdgcn_mfma_f32_16x16x32_bf16(
                        a[m], b[n], acc[m][n], 0, 0, 0);
        }
    }

    if constexpr (MODE == 0) {
        // staging path only; LDS intentionally unread (global_load_lds has
        // side effects, not DCE-able). One tiny atomic to keep kernel live.
        if (tid == 0) atomicAdd(&sink[blockIdx.x & 255], 1.0f);
        return;
    } else if constexpr (MODE == 1) {
        // fold acc (keeps MFMAs live) with minimal epilogue cost
        float f = 0.f;
        #pragma unroll
        for (int m = 0; m < 4; ++m)
            #pragma unroll
            for (int n = 0; n < 4; ++n)
                f += acc[m][n][0] + acc[m][n][1] + acc[m][n][2] + acc[m][n][3];
        #pragma unroll
        for (int off = 32; off; off >>= 1) f += __shfl_xor(f, off);
        if (lane == 0) atomicAdd(&sink[blockIdx.x & 255], f);
        return;
    } else {
        // full epilogue, into probe scratch
        const bool offdiag = (tr != tc);
        float cs[4] = {0.f, 0.f, 0.f, 0.f};
        #pragma unroll
        for (int m = 0; m < 4; ++m) {
            #pragma unroll
            for (int reg = 0; reg < 4; ++reg) {
                const int rg = row0 + wr * 64 + m * 16 + kgrp * 4 + reg;
                float rs = 0.f;
                #pragma unroll
                for (int n = 0; n < 4; ++n) {
                    const int cg = col0 + wc * 64 + n * 16 + r16;
                    float e = __expf(acc[m][n][reg] * INV_T);
                    if (rg == cg) e = 0.f;
                    rs += e;
                    cs[n] += e;
                }
                rs += __shfl_xor(rs, 1);
                rs += __shfl_xor(rs, 2);
                rs += __shfl_xor(rs, 4);
                rs += __shfl_xor(rs, 8);
                if (r16 == 0) atomicAdd(&pden[rg], rs);
            }
        }
        if (offdiag) {
            #pragma unroll
            for (int n = 0; n < 4; ++n) {
                cs[n] += __shfl_xor(cs[n], 16);
                cs[n] += __shfl_xor(cs[n], 32);
            }
            if (kgrp == 0) {
                #pragma unroll
                for (int n = 0; n < 4; ++n)
                    atomicAdd(&pden[col0 + wc * 64 + n * 16 + r16], cs[n]);
            }
        }
    }
}

// ---------------- kernel 3: final loss reduction ----------------
__global__ __launch_bounds__(1024) void final_kernel(
        const float* __restrict__ sim_pos, const float* __restrict__ denom,
        float* __restrict__ out) {
    const int tid = threadIdx.x;
    float s = 0.f;
    for (int i = tid; i < TWO_N; i += 1024)
        s += sim_pos[i] - logf(denom[i]);
    #pragma unroll
    for (int off = 32; off; off >>= 1) s += __shfl_down(s, off);
    __shared__ float red[16];
    const int wid = tid >> 6, lane = tid & 63;
    if (lane == 0) red[wid] = s;
    __syncthreads();
    if (tid == 0) {
        float t = 0.f;
        #pragma unroll
        for (int w = 0; w < 16; ++w) t += red[w];
        out[0] = -t / (float)TWO_N;
    }
}

extern "C" void kernel_launch(void* const* d_in, const int* in_sizes, int n_in,
                              void* d_out, int out_size, void* d_ws, size_t ws_size,
                              hipStream_t stream) {
    const float* z_i = (const float*)d_in[0];
    const float* z_j = (const float*)d_in[1];
    float* out = (float*)d_out;

    ushort* znb      = (ushort*)d_ws;                                  // 4 MB
    float*  sim_pos  = (float*)((char*)d_ws + (size_t)TWO_N * D * 2);  // 32 KB
    float*  denom    = sim_pos + TWO_N;                                // 32 KB
    float*  pden     = denom + TWO_N;                                  // 32 KB probe scratch
    float*  sink     = pden + TWO_N;                                   // 1 KB probe sink

    norm_pos_kernel<<<NHALF / 4, 256, 0, stream>>>(z_i, z_j, znb, sim_pos, denom);
    gemm_denom_kernel<<<NTRI, 256, 0, stream>>>(znb, denom);
    final_kernel<<<1, 1024, 0, stream>>>(sim_pos, denom, out);

    // ---- quarter-scale ablation probes (read-only on znb, write scratch) ----
    gemm_probe<0><<<NPROBE, 256, 0, stream>>>(znb, pden, sink);
    gemm_probe<1><<<NPROBE, 256, 0, stream>>>(znb, pden, sink);
    gemm_probe<2><<<NPROBE, 256, 0, stream>>>(znb, pden, sink);
}